// Round 6
// baseline (200.423 us; speedup 1.0000x reference)
//
#include <hip/hip_runtime.h>
#include <math.h>
#include <float.h>

#define NB 4096
#define ND 256
#define NK 25
#define EPSF 1e-8f
#define CAP 256          // per-wave candidate capacity
#define CTGT 160         // bisection target count

typedef __attribute__((ext_vector_type(8))) short bf16x8;
typedef __attribute__((ext_vector_type(4))) float f32x4;

#define GLD_LDS16(gp, lp)                                                   \
    __builtin_amdgcn_global_load_lds(                                       \
        (const __attribute__((address_space(1))) void*)(uintptr_t)(gp),     \
        (__attribute__((address_space(3))) void*)(uint32_t)(uintptr_t)(lp), \
        16, 0, 0)

__device__ inline short f2bf(float x) {
    unsigned u = __float_as_uint(x);
    return (short)((u + 0x7FFF + ((u >> 16) & 1)) >> 16);
}
__device__ inline float bf2f(short s) {
    return __uint_as_float(((unsigned)(unsigned short)s) << 16);
}

// ---------------------------------------------------------------- prep: hi/lo bf16 split + ||f||^2
__global__ __launch_bounds__(64) void prep_kernel(const float* __restrict__ f,
                                                  short* __restrict__ fhl,
                                                  float* __restrict__ sq) {
    int row  = blockIdx.x;
    int lane = threadIdx.x;
    float4 v = ((const float4*)(f + (size_t)row * ND))[lane];
    float acc = v.x * v.x + v.y * v.y + v.z * v.z + v.w * v.w;
    float vv[4] = {v.x, v.y, v.z, v.w};
    short h[4], l[4];
#pragma unroll
    for (int e = 0; e < 4; ++e) {
        h[e] = f2bf(vv[e]);
        l[e] = f2bf(vv[e] - bf2f(h[e]));
    }
    *(short4*)(fhl + (size_t)row * 512 + lane * 4)       = make_short4(h[0], h[1], h[2], h[3]);
    *(short4*)(fhl + (size_t)row * 512 + 256 + lane * 4) = make_short4(l[0], l[1], l[2], l[3]);
#pragma unroll
    for (int off = 32; off; off >>= 1) acc += __shfl_down(acc, off);
    if (lane == 0) sq[row] = acc;
}

// ---------------------------------------------------------------- MFMA Gram + dist epilogue
#define BM 128
#define BK 64
__global__ __launch_bounds__(256) void gram_kernel(const short* __restrict__ fhl,
                                                   const float* __restrict__ sq,
                                                   float* __restrict__ dist) {
    __shared__ __align__(16) short As[BM * BK];
    __shared__ __align__(16) short Bs[BM * BK];
    int b   = blockIdx.x;
    int ti  = (b >> 5) * BM;
    int tj  = (b & 31) * BM;
    int tid = threadIdx.x;
    int w = tid >> 6, lane = tid & 63;
    int wr = w >> 1, wc = w & 1;
    int fr = lane & 15, fq = lane >> 4;

    f32x4 acc[4][4];
#pragma unroll
    for (int m = 0; m < 4; ++m)
#pragma unroll
        for (int n = 0; n < 4; ++n) acc[m][n] = (f32x4){0.f, 0.f, 0.f, 0.f};

    int srow = lane >> 3;
    int scol = (lane & 7) * 8;

    for (int s = 0; s < 12; ++s) {
        int k0 = s * 64;
        int kA = (k0 < 512) ? (k0 & 255) : (k0 - 256);   // h,h,l
        int kB = (k0 < 512) ? k0 : (k0 - 512);           // h,l,h
#pragma unroll
        for (int i = 0; i < 4; ++i) {
            int c   = 4 * w + i;
            int row = c * 8 + srow;
            GLD_LDS16(fhl + (size_t)(ti + row) * 512 + kA + scol, As + c * 512);
            GLD_LDS16(fhl + (size_t)(tj + row) * 512 + kB + scol, Bs + c * 512);
        }
        __syncthreads();
#pragma unroll
        for (int kk = 0; kk < 2; ++kk) {
            bf16x8 af[4], bfr[4];
#pragma unroll
            for (int m = 0; m < 4; ++m)
                af[m] = *(const bf16x8*)(As + (wr * 64 + m * 16 + fr) * 64 + kk * 32 + fq * 8);
#pragma unroll
            for (int n = 0; n < 4; ++n)
                bfr[n] = *(const bf16x8*)(Bs + (wc * 64 + n * 16 + fr) * 64 + kk * 32 + fq * 8);
#pragma unroll
            for (int m = 0; m < 4; ++m)
#pragma unroll
                for (int n = 0; n < 4; ++n)
                    acc[m][n] = __builtin_amdgcn_mfma_f32_16x16x32_bf16(af[m], bfr[n], acc[m][n], 0, 0, 0);
        }
        __syncthreads();
    }

#pragma unroll
    for (int m = 0; m < 4; ++m) {
#pragma unroll
        for (int j = 0; j < 4; ++j) {
            int gi = ti + wr * 64 + m * 16 + fq * 4 + j;
            float si = sq[gi];
            float* drow = dist + (size_t)gi * NB + tj + wc * 64;
#pragma unroll
            for (int n = 0; n < 4; ++n) {
                float d = si + sq[tj + wc * 64 + n * 16 + fr] - 2.f * acc[m][n][j];
                drow[n * 16 + fr] = fmaxf(d, 0.f);
            }
        }
    }
}

// ---------------------------------------------------------------- wave-per-row top-25 (no barriers)
__global__ __launch_bounds__(256) void topk3_kernel(const float* __restrict__ dist,
                                                    int* __restrict__ idxk,
                                                    float* __restrict__ dk,
                                                    float* __restrict__ sigma) {
    int wid  = threadIdx.x >> 6;
    int lane = threadIdx.x & 63;
    int row  = blockIdx.x * 4 + wid;
    __shared__ float cval[4][CAP];
    __shared__ int   cidx[4][CAP];

    float v[64];
    const float4* src = (const float4*)(dist + (size_t)row * NB);
#pragma unroll
    for (int c = 0; c < 16; ++c) {
        float4 q = src[c * 64 + lane];
        v[c * 4 + 0] = q.x; v[c * 4 + 1] = q.y;
        v[c * 4 + 2] = q.z; v[c * 4 + 3] = q.w;
    }

    float mx = v[0];
#pragma unroll
    for (int e = 1; e < 64; ++e) mx = fmaxf(mx, v[e]);
#pragma unroll
    for (int off = 32; off; off >>= 1) mx = fmaxf(mx, __shfl_xor(mx, off));

    unsigned lo = 0u, hi = __float_as_uint(mx) + 1u;
    int cnt_hi = NB;
    for (int it = 0; it < 40; ++it) {
        if (cnt_hi <= CTGT || hi <= lo + 1u) break;
        unsigned mid = (lo + hi) >> 1;
        float T = __uint_as_float(mid);
        int c = 0;
#pragma unroll
        for (int e = 0; e < 64; ++e) c += (v[e] < T) ? 1 : 0;
#pragma unroll
        for (int off = 32; off; off >>= 1) c += __shfl_xor(c, off);
        if (c >= NK) { hi = mid; cnt_hi = c; } else { lo = mid; }
    }

    float Thi = __uint_as_float(hi);
    unsigned long long ltmask = (1ull << lane) - 1ull;
    int cnt = 0;
#pragma unroll
    for (int e = 0; e < 64; ++e) {
        bool p = (v[e] < Thi);
        unsigned long long m = __ballot(p);
        if (p) {
            int pos = cnt + __popcll(m & ltmask);
            if (pos < CAP) {
                cval[wid][pos] = v[e];
                cidx[wid][pos] = ((e >> 2) * 64 + lane) * 4 + (e & 3);
            }
        }
        cnt += __popcll(m);
    }
    cnt = min(cnt, CAP);

    float ssum = 0.f;
    for (int it = 0; it < NK; ++it) {
        float bv = FLT_MAX; int bi = NB; int bp = -1;
        for (int r = lane; r < cnt; r += 64) {
            float cv = cval[wid][r]; int ci = cidx[wid][r];
            if (cv < bv || (cv == bv && ci < bi)) { bv = cv; bi = ci; bp = r; }
        }
#pragma unroll
        for (int off = 32; off; off >>= 1) {
            float ov = __shfl_xor(bv, off);
            int   oi = __shfl_xor(bi, off);
            int   op = __shfl_xor(bp, off);
            if (ov < bv || (ov == bv && oi < bi)) { bv = ov; bi = oi; bp = op; }
        }
        if (lane == 0) {
            idxk[row * NK + it] = bi;
            dk[row * NK + it]   = bv;
            cval[wid][bp] = FLT_MAX;
        }
        ssum += sqrtf(bv + EPSF);
    }
    if (lane == 0) sigma[row] = ssum * (1.0f / NK);
}

// ---------------------------------------------------------------- P rows + score-sorted prefix tables
__global__ __launch_bounds__(64) void buildp_kernel(const int* __restrict__ idxk,
                                                    const float* __restrict__ dk,
                                                    const float* __restrict__ sigma,
                                                    const int* __restrict__ labels,
                                                    const float* __restrict__ scores,
                                                    float* __restrict__ pval,
                                                    float* __restrict__ bs,
                                                    float2* __restrict__ cs) {
    int row  = blockIdx.x;
    int lane = threadIdx.x;
    __shared__ float sb[32];
    __shared__ float sp[32];

    float w = 0.f;
    int j = 0;
    if (lane < NK) {
        j = idxk[row * NK + lane];
        bool mut = false;
        for (int n = 0; n < NK; ++n) mut |= (idxk[j * NK + n] == row);
        bool dir = labels[row] <= labels[j];
        float sij = sigma[row] * sigma[j] + EPSF;
        w = (mut && dir) ? expf(-dk[row * NK + lane] / sij) : 0.f;
        if (j == row) w += 1.f;
    }
    float rs = w;
#pragma unroll
    for (int off = 32; off; off >>= 1) rs += __shfl_down(rs, off);
    rs = __shfl(rs, 0);
    float pv = (lane < NK) ? w / (rs + EPSF) : 0.f;
    if (lane < NK) pval[row * NK + lane] = pv;

    float sj = (lane < NK) ? scores[j] : FLT_MAX;
    int rank = 0;
#pragma unroll
    for (int u = 0; u < NK; ++u) {
        float su = __shfl(sj, u);
        rank += (su < sj || (su == sj && u < lane)) ? 1 : 0;
    }
    if (lane < 32) { sb[lane] = FLT_MAX; sp[lane] = 0.f; }
    __syncthreads();
    if (lane < NK) { sb[rank] = sj; sp[rank] = pv; }
    __syncthreads();

    float b = sb[lane & 31];
    float p = sp[lane & 31];
    float c  = p;
    float s2 = p * b;
#pragma unroll
    for (int off = 1; off < 32; off <<= 1) {
        float oc = __shfl_up(c, off);
        float os = __shfl_up(s2, off);
        if (lane >= off) { c += oc; s2 += os; }
    }
    float ce = __shfl_up(c, 1);
    float se = __shfl_up(s2, 1);
    if (lane == 0) { ce = 0.f; se = 0.f; }
    if (lane < 32) {
        bs[row * 32 + lane] = b;
        cs[row * 32 + lane] = make_float2(ce, se);
    }
}

// ---------------------------------------------------------------- hval: per-j G/H at the 25 needed points
// Gval[j][u] = G_j(s_idxk[j][u]);  Hval[j][u] = sum_n pval[j][n] * G_{idxk[j][n]}(s_idxk[j][u])
// Every eval point the loss ever needs is one of these (mutual => i in idxk[j]; self at slot 0).
__global__ __launch_bounds__(256) void hval_kernel(const int* __restrict__ idxk,
                                                   const float* __restrict__ pval,
                                                   const float* __restrict__ scores,
                                                   const float* __restrict__ bs,
                                                   const float2* __restrict__ cs,
                                                   float* __restrict__ Gval,
                                                   float* __restrict__ Hval) {
    int wid  = threadIdx.x >> 6;
    int lane = threadIdx.x & 63;
    int j    = blockIdx.x * 4 + wid;
    __shared__ float2 slab[4][NK][26];           // per-wave cs cache: 4*5200B

    int  ln = (lane < NK) ? lane : NK - 1;       // clamp; inactive lanes weight 0
    int  q  = idxk[j * NK + ln];
    float p = (lane < NK) ? pval[j * NK + lane] : 0.f;
    float sqv = scores[q];                       // eval point owned by this lane

    // lane's q-table: b into VGPRs (28 incl. FLT_MAX pads), cs into LDS
    float4 bq[7];
    const float4* b4 = (const float4*)(bs + q * 32);
#pragma unroll
    for (int t = 0; t < 7; ++t) bq[t] = b4[t];
    const float4* c4 = (const float4*)(cs + q * 32);
    if (lane < NK) {
#pragma unroll
        for (int t = 0; t < 13; ++t)
            *(float4*)&slab[wid][lane][t * 2] = c4[t];
    }

    // Gval: lane u evaluates j's own table at x = s_{q_u} (its own sqv)
    float bjj = bs[j * 32 + lane];               // j's sorted scores (pads FLT_MAX)
    int posj = 0;
#pragma unroll
    for (int r = 0; r < NK; ++r)
        posj += (__shfl(bjj, r) < sqv) ? 1 : 0;
    float2 cj = cs[j * 32 + posj];
    if (lane < NK) Gval[j * 32 + lane] = sqv * cj.x - cj.y;

    __syncthreads();                             // slab visible (same-lane anyway)

    // Hval: serial over the 25 eval points, all lanes parallel over n
    for (int u = 0; u < NK; ++u) {
        float x = __shfl(sqv, u);
        int pos = 0;
#pragma unroll
        for (int t = 0; t < 7; ++t) {
            float4 b = bq[t];
            pos += (b.x < x) + (b.y < x) + (b.z < x) + (b.w < x);
        }
        float2 ch = slab[wid][ln][pos];
        float g = p * (x * ch.x - ch.y);
#pragma unroll
        for (int off = 32; off; off >>= 1) g += __shfl_xor(g, off);
        if (lane == 0) Hval[j * 32 + u] = g;
    }
}

// ---------------------------------------------------------------- init out
__global__ void init_kernel(float* __restrict__ out) { out[0] = 0.f; }

// ---------------------------------------------------------------- final loss: wave per i, table lookups
__global__ __launch_bounds__(256) void loss_kernel(const float* __restrict__ scores,
                                                   const int* __restrict__ idxk,
                                                   const float* __restrict__ pval,
                                                   const float* __restrict__ Gval,
                                                   const float* __restrict__ Hval,
                                                   float* __restrict__ out) {
    int wid  = threadIdx.x >> 6;
    int lane = threadIdx.x & 63;
    int i    = blockIdx.x * 4 + wid;
    float si = scores[i];
    float acc = 0.f;
    if (lane < NK) {
        int   jm = idxk[i * NK + lane];
        float pm = pval[i * NK + lane];
        float sj = scores[jm];
        int slot = -1;
        const int* row = idxk + jm * NK;
#pragma unroll
        for (int n = 0; n < NK; ++n)
            if (row[n] == i) slot = n;
        float g = 0.f, h = 0.f;
        if (slot >= 0) {
            g = Gval[jm * 32 + slot];
            h = Hval[jm * 32 + slot];
        }
        acc = pm * (fmaxf(si - sj, 0.f) + 0.5f * g + (1.f / 3.f) * h);
    }
#pragma unroll
    for (int off = 32; off; off >>= 1) acc += __shfl_xor(acc, off);
    if (lane == 0) atomicAdd(out, acc * (1.0f / NB));
}

// ---------------------------------------------------------------- launch
extern "C" void kernel_launch(void* const* d_in, const int* in_sizes, int n_in,
                              void* d_out, int out_size, void* d_ws, size_t ws_size,
                              hipStream_t stream) {
    const float* features = (const float*)d_in[0];
    const float* scores   = (const float*)d_in[1];
    const int*   labels   = (const int*)d_in[2];
    float* out = (float*)d_out;

    char* ws = (char*)d_ws;
    size_t off = 0;
    float*  dist  = (float*) (ws + off); off += (size_t)NB * NB * 4;
    short*  fhl   = (short*) (ws + off); off += (size_t)NB * 512 * 2;
    float*  sq    = (float*) (ws + off); off += (size_t)NB * 4;
    int*    idxk  = (int*)   (ws + off); off += (size_t)NB * NK * 4;
    float*  dk    = (float*) (ws + off); off += (size_t)NB * NK * 4;
    float*  sigma = (float*) (ws + off); off += (size_t)NB * 4;
    float*  pval  = (float*) (ws + off); off += (size_t)NB * NK * 4;
    float*  bs    = (float*) (ws + off); off += (size_t)NB * 32 * 4;
    float2* cs    = (float2*)(ws + off); off += (size_t)NB * 32 * 8;
    float*  Gval  = (float*) (ws + off); off += (size_t)NB * 32 * 4;
    float*  Hval  = (float*) (ws + off); off += (size_t)NB * 32 * 4;

    init_kernel<<<1, 1, 0, stream>>>(out);
    prep_kernel<<<NB, 64, 0, stream>>>(features, fhl, sq);
    gram_kernel<<<(NB / BM) * (NB / BM), 256, 0, stream>>>(fhl, sq, dist);
    topk3_kernel<<<NB / 4, 256, 0, stream>>>(dist, idxk, dk, sigma);
    buildp_kernel<<<NB, 64, 0, stream>>>(idxk, dk, sigma, labels, scores, pval, bs, cs);
    hval_kernel<<<NB / 4, 256, 0, stream>>>(idxk, pval, scores, bs, cs, Gval, Hval);
    loss_kernel<<<NB / 4, 256, 0, stream>>>(scores, idxk, pval, Gval, Hval, out);
}

// Round 7
// 175.822 us; speedup vs baseline: 1.1399x; 1.1399x over previous
//
#include <hip/hip_runtime.h>
#include <math.h>
#include <float.h>

#define NB 4096
#define ND 256
#define NK 25
#define EPSF 1e-8f
#define CAP 256          // per-wave candidate capacity
#define CTGT 160         // bisection target count

typedef __attribute__((ext_vector_type(8))) short bf16x8;
typedef __attribute__((ext_vector_type(4))) float f32x4;

#define GLD_LDS16(gp, lp)                                                   \
    __builtin_amdgcn_global_load_lds(                                       \
        (const __attribute__((address_space(1))) void*)(uintptr_t)(gp),     \
        (__attribute__((address_space(3))) void*)(uint32_t)(uintptr_t)(lp), \
        16, 0, 0)

__device__ inline short f2bf(float x) {
    unsigned u = __float_as_uint(x);
    return (short)((u + 0x7FFF + ((u >> 16) & 1)) >> 16);
}

// ---------------------------------------------------------------- prep: bf16 cast + ||f||^2 (exact fp32)
__global__ __launch_bounds__(64) void prep_kernel(const float* __restrict__ f,
                                                  short* __restrict__ fh,
                                                  float* __restrict__ sq) {
    int row  = blockIdx.x;
    int lane = threadIdx.x;
    float4 v = ((const float4*)(f + (size_t)row * ND))[lane];
    float acc = v.x * v.x + v.y * v.y + v.z * v.z + v.w * v.w;
    *(short4*)(fh + (size_t)row * ND + lane * 4) =
        make_short4(f2bf(v.x), f2bf(v.y), f2bf(v.z), f2bf(v.w));
#pragma unroll
    for (int off = 32; off; off >>= 1) acc += __shfl_down(acc, off);
    if (lane == 0) sq[row] = acc;
}

// ---------------------------------------------------------------- MFMA Gram (hi-only, K=256) + dist epilogue
#define BM 128
#define BK 64
__global__ __launch_bounds__(256) void gram_kernel(const short* __restrict__ fh,
                                                   const float* __restrict__ sq,
                                                   float* __restrict__ dist) {
    __shared__ __align__(16) short As[BM * BK];
    __shared__ __align__(16) short Bs[BM * BK];
    int b   = blockIdx.x;
    int ti  = (b >> 5) * BM;
    int tj  = (b & 31) * BM;
    int tid = threadIdx.x;
    int w = tid >> 6, lane = tid & 63;
    int wr = w >> 1, wc = w & 1;
    int fr = lane & 15, fq = lane >> 4;

    f32x4 acc[4][4];
#pragma unroll
    for (int m = 0; m < 4; ++m)
#pragma unroll
        for (int n = 0; n < 4; ++n) acc[m][n] = (f32x4){0.f, 0.f, 0.f, 0.f};

    int srow = lane >> 3;
    int scol = (lane & 7) * 8;

    for (int s = 0; s < 4; ++s) {
        int k0 = s * 64;
#pragma unroll
        for (int i = 0; i < 4; ++i) {
            int c   = 4 * w + i;
            int row = c * 8 + srow;
            GLD_LDS16(fh + (size_t)(ti + row) * ND + k0 + scol, As + c * 512);
            GLD_LDS16(fh + (size_t)(tj + row) * ND + k0 + scol, Bs + c * 512);
        }
        __syncthreads();
#pragma unroll
        for (int kk = 0; kk < 2; ++kk) {
            bf16x8 af[4], bfr[4];
#pragma unroll
            for (int m = 0; m < 4; ++m)
                af[m] = *(const bf16x8*)(As + (wr * 64 + m * 16 + fr) * 64 + kk * 32 + fq * 8);
#pragma unroll
            for (int n = 0; n < 4; ++n)
                bfr[n] = *(const bf16x8*)(Bs + (wc * 64 + n * 16 + fr) * 64 + kk * 32 + fq * 8);
#pragma unroll
            for (int m = 0; m < 4; ++m)
#pragma unroll
                for (int n = 0; n < 4; ++n)
                    acc[m][n] = __builtin_amdgcn_mfma_f32_16x16x32_bf16(af[m], bfr[n], acc[m][n], 0, 0, 0);
        }
        __syncthreads();
    }

#pragma unroll
    for (int m = 0; m < 4; ++m) {
#pragma unroll
        for (int j = 0; j < 4; ++j) {
            int gi = ti + wr * 64 + m * 16 + fq * 4 + j;
            float si = sq[gi];
            float* drow = dist + (size_t)gi * NB + tj + wc * 64;
#pragma unroll
            for (int n = 0; n < 4; ++n) {
                float d = si + sq[tj + wc * 64 + n * 16 + fr] - 2.f * acc[m][n][j];
                drow[n * 16 + fr] = fmaxf(d, 0.f);
            }
        }
    }
}

// ---------------------------------------------------------------- wave-per-row top-25, mean-seeded linear bisection
__global__ __launch_bounds__(256) void topk3_kernel(const float* __restrict__ dist,
                                                    int* __restrict__ idxk,
                                                    float* __restrict__ dk,
                                                    float* __restrict__ sigma) {
    int wid  = threadIdx.x >> 6;
    int lane = threadIdx.x & 63;
    int row  = blockIdx.x * 4 + wid;
    __shared__ float cval[4][CAP];
    __shared__ int   cidx[4][CAP];

    float v[64];
    const float4* src = (const float4*)(dist + (size_t)row * NB);
#pragma unroll
    for (int c = 0; c < 16; ++c) {
        float4 q = src[c * 64 + lane];
        v[c * 4 + 0] = q.x; v[c * 4 + 1] = q.y;
        v[c * 4 + 2] = q.z; v[c * 4 + 3] = q.w;
    }

    // wave max + mean
    float mx = v[0], sm = v[0];
#pragma unroll
    for (int e = 1; e < 64; ++e) { mx = fmaxf(mx, v[e]); sm += v[e]; }
#pragma unroll
    for (int off = 32; off; off >>= 1) {
        mx = fmaxf(mx, __shfl_xor(mx, off));
        sm += __shfl_xor(sm, off);
    }
    float mu = sm * (1.0f / NB);

    // initial hi = mu
    int c0 = 0;
#pragma unroll
    for (int e = 0; e < 64; ++e) c0 += (v[e] < mu) ? 1 : 0;
#pragma unroll
    for (int off = 32; off; off >>= 1) c0 += __shfl_xor(c0, off);
    float lo = 0.f, hi = mu;
    int cnt_hi = c0;
    if (cnt_hi < NK) { hi = mx * 1.000001f + 1e-20f; cnt_hi = NB; }   // fallback

    // linear bisection: invariant count(<lo) < NK <= count(<hi)
    for (int it = 0; it < 24; ++it) {
        if (cnt_hi <= CTGT) break;
        float mid = 0.5f * (lo + hi);
        if (mid <= lo || mid >= hi) break;       // resolution exhausted
        int c = 0;
#pragma unroll
        for (int e = 0; e < 64; ++e) c += (v[e] < mid) ? 1 : 0;
#pragma unroll
        for (int off = 32; off; off >>= 1) c += __shfl_xor(c, off);
        if (c >= NK) { hi = mid; cnt_hi = c; } else { lo = mid; }
    }

    // ballot/popc compaction of candidates < hi
    float Thi = hi;
    unsigned long long ltmask = (1ull << lane) - 1ull;
    int cnt = 0;
#pragma unroll
    for (int e = 0; e < 64; ++e) {
        bool p = (v[e] < Thi);
        unsigned long long m = __ballot(p);
        if (p) {
            int pos = cnt + __popcll(m & ltmask);
            if (pos < CAP) {
                cval[wid][pos] = v[e];
                cidx[wid][pos] = ((e >> 2) * 64 + lane) * 4 + (e & 3);
            }
        }
        cnt += __popcll(m);
    }
    cnt = min(cnt, CAP);

    // exact 25-way select among candidates, (value,index) lexicographic
    float ssum = 0.f;
    for (int it = 0; it < NK; ++it) {
        float bv = FLT_MAX; int bi = NB; int bp = -1;
        for (int r = lane; r < cnt; r += 64) {
            float cv = cval[wid][r]; int ci = cidx[wid][r];
            if (cv < bv || (cv == bv && ci < bi)) { bv = cv; bi = ci; bp = r; }
        }
#pragma unroll
        for (int off = 32; off; off >>= 1) {
            float ov = __shfl_xor(bv, off);
            int   oi = __shfl_xor(bi, off);
            int   op = __shfl_xor(bp, off);
            if (ov < bv || (ov == bv && oi < bi)) { bv = ov; bi = oi; bp = op; }
        }
        if (lane == 0) {
            idxk[row * NK + it] = bi;
            dk[row * NK + it]   = bv;
            cval[wid][bp] = FLT_MAX;
        }
        ssum += sqrtf(bv + EPSF);
    }
    if (lane == 0) sigma[row] = ssum * (1.0f / NK);
}

// ---------------------------------------------------------------- P rows + score-sorted prefix tables
__global__ __launch_bounds__(64) void buildp_kernel(const int* __restrict__ idxk,
                                                    const float* __restrict__ dk,
                                                    const float* __restrict__ sigma,
                                                    const int* __restrict__ labels,
                                                    const float* __restrict__ scores,
                                                    float* __restrict__ pval,
                                                    float* __restrict__ bs,
                                                    float2* __restrict__ cs) {
    int row  = blockIdx.x;
    int lane = threadIdx.x;
    __shared__ float sb[32];
    __shared__ float sp[32];

    float w = 0.f;
    int j = 0;
    if (lane < NK) {
        j = idxk[row * NK + lane];
        bool mut = false;
        for (int n = 0; n < NK; ++n) mut |= (idxk[j * NK + n] == row);
        bool dir = labels[row] <= labels[j];
        float sij = sigma[row] * sigma[j] + EPSF;
        w = (mut && dir) ? expf(-dk[row * NK + lane] / sij) : 0.f;
        if (j == row) w += 1.f;
    }
    float rs = w;
#pragma unroll
    for (int off = 32; off; off >>= 1) rs += __shfl_down(rs, off);
    rs = __shfl(rs, 0);
    float pv = (lane < NK) ? w / (rs + EPSF) : 0.f;
    if (lane < NK) pval[row * NK + lane] = pv;

    float sj = (lane < NK) ? scores[j] : FLT_MAX;
    int rank = 0;
#pragma unroll
    for (int u = 0; u < NK; ++u) {
        float su = __shfl(sj, u);
        rank += (su < sj || (su == sj && u < lane)) ? 1 : 0;
    }
    if (lane < 32) { sb[lane] = FLT_MAX; sp[lane] = 0.f; }
    __syncthreads();
    if (lane < NK) { sb[rank] = sj; sp[rank] = pv; }
    __syncthreads();

    float b = sb[lane & 31];
    float p = sp[lane & 31];
    float c  = p;
    float s2 = p * b;
#pragma unroll
    for (int off = 1; off < 32; off <<= 1) {
        float oc = __shfl_up(c, off);
        float os = __shfl_up(s2, off);
        if (lane >= off) { c += oc; s2 += os; }
    }
    float ce = __shfl_up(c, 1);
    float se = __shfl_up(s2, 1);
    if (lane == 0) { ce = 0.f; se = 0.f; }
    if (lane < 32) {
        bs[row * 32 + lane] = b;
        cs[row * 32 + lane] = make_float2(ce, se);
    }
}

// ---------------------------------------------------------------- hval: per-j G/H at the 25 needed points
__global__ __launch_bounds__(256) void hval_kernel(const int* __restrict__ idxk,
                                                   const float* __restrict__ pval,
                                                   const float* __restrict__ scores,
                                                   const float* __restrict__ bs,
                                                   const float2* __restrict__ cs,
                                                   float* __restrict__ Gval,
                                                   float* __restrict__ Hval) {
    int wid  = threadIdx.x >> 6;
    int lane = threadIdx.x & 63;
    int j    = blockIdx.x * 4 + wid;
    __shared__ float2 slab[4][NK][26];

    int  ln = (lane < NK) ? lane : NK - 1;
    int  q  = idxk[j * NK + ln];
    float p = (lane < NK) ? pval[j * NK + lane] : 0.f;
    float sqv = scores[q];

    float4 bq[7];
    const float4* b4 = (const float4*)(bs + q * 32);
#pragma unroll
    for (int t = 0; t < 7; ++t) bq[t] = b4[t];
    const float4* c4 = (const float4*)(cs + q * 32);
    if (lane < NK) {
#pragma unroll
        for (int t = 0; t < 13; ++t)
            *(float4*)&slab[wid][lane][t * 2] = c4[t];
    }

    float bjj = bs[j * 32 + lane];
    int posj = 0;
#pragma unroll
    for (int r = 0; r < NK; ++r)
        posj += (__shfl(bjj, r) < sqv) ? 1 : 0;
    float2 cj = cs[j * 32 + posj];
    if (lane < NK) Gval[j * 32 + lane] = sqv * cj.x - cj.y;

    __syncthreads();

    for (int u = 0; u < NK; ++u) {
        float x = __shfl(sqv, u);
        int pos = 0;
#pragma unroll
        for (int t = 0; t < 7; ++t) {
            float4 b = bq[t];
            pos += (b.x < x) + (b.y < x) + (b.z < x) + (b.w < x);
        }
        float2 ch = slab[wid][ln][pos];
        float g = p * (x * ch.x - ch.y);
#pragma unroll
        for (int off = 32; off; off >>= 1) g += __shfl_xor(g, off);
        if (lane == 0) Hval[j * 32 + u] = g;
    }
}

// ---------------------------------------------------------------- init out
__global__ void init_kernel(float* __restrict__ out) { out[0] = 0.f; }

// ---------------------------------------------------------------- final loss
__global__ __launch_bounds__(256) void loss_kernel(const float* __restrict__ scores,
                                                   const int* __restrict__ idxk,
                                                   const float* __restrict__ pval,
                                                   const float* __restrict__ Gval,
                                                   const float* __restrict__ Hval,
                                                   float* __restrict__ out) {
    int wid  = threadIdx.x >> 6;
    int lane = threadIdx.x & 63;
    int i    = blockIdx.x * 4 + wid;
    float si = scores[i];
    float acc = 0.f;
    if (lane < NK) {
        int   jm = idxk[i * NK + lane];
        float pm = pval[i * NK + lane];
        float sj = scores[jm];
        int slot = -1;
        const int* row = idxk + jm * NK;
#pragma unroll
        for (int n = 0; n < NK; ++n)
            if (row[n] == i) slot = n;
        float g = 0.f, h = 0.f;
        if (slot >= 0) {
            g = Gval[jm * 32 + slot];
            h = Hval[jm * 32 + slot];
        }
        acc = pm * (fmaxf(si - sj, 0.f) + 0.5f * g + (1.f / 3.f) * h);
    }
#pragma unroll
    for (int off = 32; off; off >>= 1) acc += __shfl_xor(acc, off);
    if (lane == 0) atomicAdd(out, acc * (1.0f / NB));
}

// ---------------------------------------------------------------- launch
extern "C" void kernel_launch(void* const* d_in, const int* in_sizes, int n_in,
                              void* d_out, int out_size, void* d_ws, size_t ws_size,
                              hipStream_t stream) {
    const float* features = (const float*)d_in[0];
    const float* scores   = (const float*)d_in[1];
    const int*   labels   = (const int*)d_in[2];
    float* out = (float*)d_out;

    char* ws = (char*)d_ws;
    size_t off = 0;
    float*  dist  = (float*) (ws + off); off += (size_t)NB * NB * 4;
    short*  fh    = (short*) (ws + off); off += (size_t)NB * ND * 2;
    float*  sq    = (float*) (ws + off); off += (size_t)NB * 4;
    int*    idxk  = (int*)   (ws + off); off += (size_t)NB * NK * 4;
    float*  dk    = (float*) (ws + off); off += (size_t)NB * NK * 4;
    float*  sigma = (float*) (ws + off); off += (size_t)NB * 4;
    float*  pval  = (float*) (ws + off); off += (size_t)NB * NK * 4;
    float*  bs    = (float*) (ws + off); off += (size_t)NB * 32 * 4;
    float2* cs    = (float2*)(ws + off); off += (size_t)NB * 32 * 8;
    float*  Gval  = (float*) (ws + off); off += (size_t)NB * 32 * 4;
    float*  Hval  = (float*) (ws + off); off += (size_t)NB * 32 * 4;

    init_kernel<<<1, 1, 0, stream>>>(out);
    prep_kernel<<<NB, 64, 0, stream>>>(features, fh, sq);
    gram_kernel<<<(NB / BM) * (NB / BM), 256, 0, stream>>>(fh, sq, dist);
    topk3_kernel<<<NB / 4, 256, 0, stream>>>(dist, idxk, dk, sigma);
    buildp_kernel<<<NB, 64, 0, stream>>>(idxk, dk, sigma, labels, scores, pval, bs, cs);
    hval_kernel<<<NB / 4, 256, 0, stream>>>(idxk, pval, scores, bs, cs, Gval, Hval);
    loss_kernel<<<NB / 4, 256, 0, stream>>>(scores, idxk, pval, Gval, Hval, out);
}

// Round 8
// 101.407 us; speedup vs baseline: 1.9764x; 1.7338x over previous
//
#include <hip/hip_runtime.h>
#include <math.h>
#include <float.h>

#define NB 4096
#define ND 256
#define NK 25
#define EPSF 1e-8f
#define CAP 256          // fallback candidate capacity

typedef __attribute__((ext_vector_type(8))) short bf16x8;
typedef __attribute__((ext_vector_type(4))) float f32x4;

#define GLD_LDS16(gp, lp)                                                   \
    __builtin_amdgcn_global_load_lds(                                       \
        (const __attribute__((address_space(1))) void*)(uintptr_t)(gp),     \
        (__attribute__((address_space(3))) void*)(uint32_t)(uintptr_t)(lp), \
        16, 0, 0)

__device__ inline short f2bf(float x) {
    unsigned u = __float_as_uint(x);
    return (short)((u + 0x7FFF + ((u >> 16) & 1)) >> 16);
}

// ---------------------------------------------------------------- prep: bf16 cast + ||f||^2 (exact fp32)
__global__ __launch_bounds__(64) void prep_kernel(const float* __restrict__ f,
                                                  short* __restrict__ fh,
                                                  float* __restrict__ sq) {
    int row  = blockIdx.x;
    int lane = threadIdx.x;
    float4 v = ((const float4*)(f + (size_t)row * ND))[lane];
    float acc = v.x * v.x + v.y * v.y + v.z * v.z + v.w * v.w;
    *(short4*)(fh + (size_t)row * ND + lane * 4) =
        make_short4(f2bf(v.x), f2bf(v.y), f2bf(v.z), f2bf(v.w));
#pragma unroll
    for (int off = 32; off; off >>= 1) acc += __shfl_down(acc, off);
    if (lane == 0) sq[row] = acc;
}

// ---------------------------------------------------------------- MFMA Gram (hi-only, K=256) + dist epilogue
#define BM 128
#define BK 64
__global__ __launch_bounds__(256) void gram_kernel(const short* __restrict__ fh,
                                                   const float* __restrict__ sq,
                                                   float* __restrict__ dist) {
    __shared__ __align__(16) short As[BM * BK];
    __shared__ __align__(16) short Bs[BM * BK];
    int b   = blockIdx.x;
    int ti  = (b >> 5) * BM;
    int tj  = (b & 31) * BM;
    int tid = threadIdx.x;
    int w = tid >> 6, lane = tid & 63;
    int wr = w >> 1, wc = w & 1;
    int fr = lane & 15, fq = lane >> 4;

    f32x4 acc[4][4];
#pragma unroll
    for (int m = 0; m < 4; ++m)
#pragma unroll
        for (int n = 0; n < 4; ++n) acc[m][n] = (f32x4){0.f, 0.f, 0.f, 0.f};

    int srow = lane >> 3;
    int scol = (lane & 7) * 8;

    for (int s = 0; s < 4; ++s) {
        int k0 = s * 64;
#pragma unroll
        for (int i = 0; i < 4; ++i) {
            int c   = 4 * w + i;
            int row = c * 8 + srow;
            GLD_LDS16(fh + (size_t)(ti + row) * ND + k0 + scol, As + c * 512);
            GLD_LDS16(fh + (size_t)(tj + row) * ND + k0 + scol, Bs + c * 512);
        }
        __syncthreads();
#pragma unroll
        for (int kk = 0; kk < 2; ++kk) {
            bf16x8 af[4], bfr[4];
#pragma unroll
            for (int m = 0; m < 4; ++m)
                af[m] = *(const bf16x8*)(As + (wr * 64 + m * 16 + fr) * 64 + kk * 32 + fq * 8);
#pragma unroll
            for (int n = 0; n < 4; ++n)
                bfr[n] = *(const bf16x8*)(Bs + (wc * 64 + n * 16 + fr) * 64 + kk * 32 + fq * 8);
#pragma unroll
            for (int m = 0; m < 4; ++m)
#pragma unroll
                for (int n = 0; n < 4; ++n)
                    acc[m][n] = __builtin_amdgcn_mfma_f32_16x16x32_bf16(af[m], bfr[n], acc[m][n], 0, 0, 0);
        }
        __syncthreads();
    }

#pragma unroll
    for (int m = 0; m < 4; ++m) {
#pragma unroll
        for (int j = 0; j < 4; ++j) {
            int gi = ti + wr * 64 + m * 16 + fq * 4 + j;
            float si = sq[gi];
            float* drow = dist + (size_t)gi * NB + tj + wc * 64;
#pragma unroll
            for (int n = 0; n < 4; ++n) {
                float d = si + sq[tj + wc * 64 + n * 16 + fr] - 2.f * acc[m][n][j];
                drow[n * 16 + fr] = fmaxf(d, 0.f);
            }
        }
    }
}

// ---------------------------------------------------------------- wave-per-row top-25: bisect to <=64, rank-select
__global__ __launch_bounds__(256) void topk4_kernel(const float* __restrict__ dist,
                                                    int* __restrict__ idxk,
                                                    float* __restrict__ dk,
                                                    float* __restrict__ sigma) {
    int wid  = threadIdx.x >> 6;
    int lane = threadIdx.x & 63;
    int row  = blockIdx.x * 4 + wid;
    __shared__ float cval[4][CAP];
    __shared__ int   cidx[4][CAP];

    float v[64];
    const float4* src = (const float4*)(dist + (size_t)row * NB);
#pragma unroll
    for (int c = 0; c < 16; ++c) {
        float4 q = src[c * 64 + lane];
        v[c * 4 + 0] = q.x; v[c * 4 + 1] = q.y;
        v[c * 4 + 2] = q.z; v[c * 4 + 3] = q.w;
    }

    // wave max + mean
    float mx = v[0], sm = v[0];
#pragma unroll
    for (int e = 1; e < 64; ++e) { mx = fmaxf(mx, v[e]); sm += v[e]; }
#pragma unroll
    for (int off = 32; off; off >>= 1) {
        mx = fmaxf(mx, __shfl_xor(mx, off));
        sm += __shfl_xor(sm, off);
    }
    float mu = sm * (1.0f / NB);

    int c0 = 0;
#pragma unroll
    for (int e = 0; e < 64; ++e) c0 += (v[e] < mu) ? 1 : 0;
#pragma unroll
    for (int off = 32; off; off >>= 1) c0 += __shfl_xor(c0, off);
    float lo = 0.f, hi = mu;
    int cnt_hi = c0;
    if (cnt_hi < NK) { hi = mx * 1.000001f + 1e-20f; cnt_hi = NB; }   // fallback seed

    // bisection: invariant count(<lo) < NK <= count(<hi); drive count(<hi) <= 64
    for (int it = 0; it < 40; ++it) {
        if (cnt_hi <= 64) break;
        float mid = 0.5f * (lo + hi);
        if (mid <= lo || mid >= hi) break;       // resolution exhausted (ties)
        int c = 0;
#pragma unroll
        for (int e = 0; e < 64; ++e) c += (v[e] < mid) ? 1 : 0;
#pragma unroll
        for (int off = 32; off; off >>= 1) c += __shfl_xor(c, off);
        if (c >= NK) { hi = mid; cnt_hi = c; } else { lo = mid; }
    }

    // ballot/popc compaction of candidates < hi
    float Thi = hi;
    unsigned long long ltmask = (1ull << lane) - 1ull;
    int cnt = 0;
#pragma unroll
    for (int e = 0; e < 64; ++e) {
        bool p = (v[e] < Thi);
        unsigned long long m = __ballot(p);
        if (p) {
            int pos = cnt + __popcll(m & ltmask);
            if (pos < CAP) {
                cval[wid][pos] = v[e];
                cidx[wid][pos] = ((e >> 2) * 64 + lane) * 4 + (e & 3);
            }
        }
        cnt += __popcll(m);
    }
    cnt = min(cnt, CAP);

    if (cnt <= 64) {
        // one candidate per lane; rank by (value,index); rank<NK are the top-25
        float x  = (lane < cnt) ? cval[wid][lane] : FLT_MAX;
        int   xi = (lane < cnt) ? cidx[wid][lane] : 0x7fffffff;
        int rank = 0;
        for (int s = 1; s < 64; ++s) {
            int   sl = (lane + s) & 63;
            float y  = __shfl(x, sl);
            int   yi = __shfl(xi, sl);
            rank += (y < x || (y == x && yi < xi)) ? 1 : 0;
        }
        bool sel = (lane < cnt) && (rank < NK);
        if (sel) {
            idxk[row * NK + rank] = xi;
            dk[row * NK + rank]   = x;
        }
        float t = sel ? sqrtf(x + EPSF) : 0.f;
#pragma unroll
        for (int off = 32; off; off >>= 1) t += __shfl_xor(t, off);
        if (lane == 0) sigma[row] = t * (1.0f / NK);
    } else {
        // tie-overflow fallback: serial exact select (rare)
        float ssum = 0.f;
        for (int it = 0; it < NK; ++it) {
            float bv = FLT_MAX; int bi = NB; int bp = -1;
            for (int r = lane; r < cnt; r += 64) {
                float cv = cval[wid][r]; int ci = cidx[wid][r];
                if (cv < bv || (cv == bv && ci < bi)) { bv = cv; bi = ci; bp = r; }
            }
#pragma unroll
            for (int off = 32; off; off >>= 1) {
                float ov = __shfl_xor(bv, off);
                int   oi = __shfl_xor(bi, off);
                int   op = __shfl_xor(bp, off);
                if (ov < bv || (ov == bv && oi < bi)) { bv = ov; bi = oi; bp = op; }
            }
            if (lane == 0) {
                idxk[row * NK + it] = bi;
                dk[row * NK + it]   = bv;
                cval[wid][bp] = FLT_MAX;
            }
            bv = __shfl(bv, 0);
            ssum += sqrtf(bv + EPSF);
        }
        if (lane == 0) sigma[row] = ssum * (1.0f / NK);
    }
}

// ---------------------------------------------------------------- P rows + score-sorted prefix tables
__global__ __launch_bounds__(64) void buildp_kernel(const int* __restrict__ idxk,
                                                    const float* __restrict__ dk,
                                                    const float* __restrict__ sigma,
                                                    const int* __restrict__ labels,
                                                    const float* __restrict__ scores,
                                                    float* __restrict__ pval,
                                                    float* __restrict__ bs,
                                                    float2* __restrict__ cs) {
    int row  = blockIdx.x;
    int lane = threadIdx.x;
    __shared__ float sb[32];
    __shared__ float sp[32];

    float w = 0.f;
    int j = 0;
    if (lane < NK) {
        j = idxk[row * NK + lane];
        bool mut = false;
        for (int n = 0; n < NK; ++n) mut |= (idxk[j * NK + n] == row);
        bool dir = labels[row] <= labels[j];
        float sij = sigma[row] * sigma[j] + EPSF;
        w = (mut && dir) ? expf(-dk[row * NK + lane] / sij) : 0.f;
        if (j == row) w += 1.f;
    }
    float rs = w;
#pragma unroll
    for (int off = 32; off; off >>= 1) rs += __shfl_down(rs, off);
    rs = __shfl(rs, 0);
    float pv = (lane < NK) ? w / (rs + EPSF) : 0.f;
    if (lane < NK) pval[row * NK + lane] = pv;

    float sj = (lane < NK) ? scores[j] : FLT_MAX;
    int rank = 0;
#pragma unroll
    for (int u = 0; u < NK; ++u) {
        float su = __shfl(sj, u);
        rank += (su < sj || (su == sj && u < lane)) ? 1 : 0;
    }
    if (lane < 32) { sb[lane] = FLT_MAX; sp[lane] = 0.f; }
    __syncthreads();
    if (lane < NK) { sb[rank] = sj; sp[rank] = pv; }
    __syncthreads();

    float b = sb[lane & 31];
    float p = sp[lane & 31];
    float c  = p;
    float s2 = p * b;
#pragma unroll
    for (int off = 1; off < 32; off <<= 1) {
        float oc = __shfl_up(c, off);
        float os = __shfl_up(s2, off);
        if (lane >= off) { c += oc; s2 += os; }
    }
    float ce = __shfl_up(c, 1);
    float se = __shfl_up(s2, 1);
    if (lane == 0) { ce = 0.f; se = 0.f; }
    if (lane < 32) {
        bs[row * 32 + lane] = b;
        cs[row * 32 + lane] = make_float2(ce, se);
    }
}

// ---------------------------------------------------------------- hval: per-j G/H at the 25 needed points
__global__ __launch_bounds__(256) void hval_kernel(const int* __restrict__ idxk,
                                                   const float* __restrict__ pval,
                                                   const float* __restrict__ scores,
                                                   const float* __restrict__ bs,
                                                   const float2* __restrict__ cs,
                                                   float* __restrict__ Gval,
                                                   float* __restrict__ Hval) {
    int wid  = threadIdx.x >> 6;
    int lane = threadIdx.x & 63;
    int j    = blockIdx.x * 4 + wid;
    __shared__ float2 slab[4][NK][26];

    int  ln = (lane < NK) ? lane : NK - 1;
    int  q  = idxk[j * NK + ln];
    float p = (lane < NK) ? pval[j * NK + lane] : 0.f;
    float sqv = scores[q];

    float4 bq[7];
    const float4* b4 = (const float4*)(bs + q * 32);
#pragma unroll
    for (int t = 0; t < 7; ++t) bq[t] = b4[t];
    const float4* c4 = (const float4*)(cs + q * 32);
    if (lane < NK) {
#pragma unroll
        for (int t = 0; t < 13; ++t)
            *(float4*)&slab[wid][lane][t * 2] = c4[t];
    }

    float bjj = bs[j * 32 + lane];
    int posj = 0;
#pragma unroll
    for (int r = 0; r < NK; ++r)
        posj += (__shfl(bjj, r) < sqv) ? 1 : 0;
    float2 cj = cs[j * 32 + posj];
    if (lane < NK) Gval[j * 32 + lane] = sqv * cj.x - cj.y;

    __syncthreads();

    for (int u = 0; u < NK; ++u) {
        float x = __shfl(sqv, u);
        int pos = 0;
#pragma unroll
        for (int t = 0; t < 7; ++t) {
            float4 b = bq[t];
            pos += (b.x < x) + (b.y < x) + (b.z < x) + (b.w < x);
        }
        float2 ch = slab[wid][ln][pos];
        float g = p * (x * ch.x - ch.y);
#pragma unroll
        for (int off = 32; off; off >>= 1) g += __shfl_xor(g, off);
        if (lane == 0) Hval[j * 32 + u] = g;
    }
}

// ---------------------------------------------------------------- final loss: per-wave partial (no atomics)
__global__ __launch_bounds__(256) void loss_kernel(const float* __restrict__ scores,
                                                   const int* __restrict__ idxk,
                                                   const float* __restrict__ pval,
                                                   const float* __restrict__ Gval,
                                                   const float* __restrict__ Hval,
                                                   float* __restrict__ partial) {
    int wid  = threadIdx.x >> 6;
    int lane = threadIdx.x & 63;
    int i    = blockIdx.x * 4 + wid;
    float si = scores[i];
    float acc = 0.f;
    if (lane < NK) {
        int   jm = idxk[i * NK + lane];
        float pm = pval[i * NK + lane];
        float sj = scores[jm];
        int slot = -1;
        const int* row = idxk + jm * NK;
#pragma unroll
        for (int n = 0; n < NK; ++n)
            if (row[n] == i) slot = n;
        float g = 0.f, h = 0.f;
        if (slot >= 0) {
            g = Gval[jm * 32 + slot];
            h = Hval[jm * 32 + slot];
        }
        acc = pm * (fmaxf(si - sj, 0.f) + 0.5f * g + (1.f / 3.f) * h);
    }
#pragma unroll
    for (int off = 32; off; off >>= 1) acc += __shfl_xor(acc, off);
    if (lane == 0) partial[i] = acc;
}

// ---------------------------------------------------------------- final reduce: 1 block sums 4096 partials
__global__ __launch_bounds__(256) void reduce_kernel(const float* __restrict__ partial,
                                                     float* __restrict__ out) {
    int tid = threadIdx.x;
    __shared__ float red[4];
    float a = 0.f;
    for (int t = tid; t < NB / 4; t += 256) {
        float4 p = ((const float4*)partial)[t];
        a += p.x + p.y + p.z + p.w;
    }
#pragma unroll
    for (int off = 32; off; off >>= 1) a += __shfl_xor(a, off);
    if ((tid & 63) == 0) red[tid >> 6] = a;
    __syncthreads();
    if (tid == 0) out[0] = (red[0] + red[1] + red[2] + red[3]) * (1.0f / NB);
}

// ---------------------------------------------------------------- launch
extern "C" void kernel_launch(void* const* d_in, const int* in_sizes, int n_in,
                              void* d_out, int out_size, void* d_ws, size_t ws_size,
                              hipStream_t stream) {
    const float* features = (const float*)d_in[0];
    const float* scores   = (const float*)d_in[1];
    const int*   labels   = (const int*)d_in[2];
    float* out = (float*)d_out;

    char* ws = (char*)d_ws;
    size_t off = 0;
    float*  dist    = (float*) (ws + off); off += (size_t)NB * NB * 4;
    short*  fh      = (short*) (ws + off); off += (size_t)NB * ND * 2;
    float*  sq      = (float*) (ws + off); off += (size_t)NB * 4;
    int*    idxk    = (int*)   (ws + off); off += (size_t)NB * NK * 4;
    float*  dk      = (float*) (ws + off); off += (size_t)NB * NK * 4;
    float*  sigma   = (float*) (ws + off); off += (size_t)NB * 4;
    float*  pval    = (float*) (ws + off); off += (size_t)NB * NK * 4;
    float*  bs      = (float*) (ws + off); off += (size_t)NB * 32 * 4;
    float2* cs      = (float2*)(ws + off); off += (size_t)NB * 32 * 8;
    float*  Gval    = (float*) (ws + off); off += (size_t)NB * 32 * 4;
    float*  Hval    = (float*) (ws + off); off += (size_t)NB * 32 * 4;
    float*  partial = (float*) (ws + off); off += (size_t)NB * 4;

    prep_kernel<<<NB, 64, 0, stream>>>(features, fh, sq);
    gram_kernel<<<(NB / BM) * (NB / BM), 256, 0, stream>>>(fh, sq, dist);
    topk4_kernel<<<NB / 4, 256, 0, stream>>>(dist, idxk, dk, sigma);
    buildp_kernel<<<NB, 64, 0, stream>>>(idxk, dk, sigma, labels, scores, pval, bs, cs);
    hval_kernel<<<NB / 4, 256, 0, stream>>>(idxk, pval, scores, bs, cs, Gval, Hval);
    loss_kernel<<<NB / 4, 256, 0, stream>>>(scores, idxk, pval, Gval, Hval, partial);
    reduce_kernel<<<1, 256, 0, stream>>>(partial, out);
}